// Round 11
// baseline (353.379 us; speedup 1.0000x reference)
//
#include <hip/hip_runtime.h>

// Problem constants (reference: shape (2,1,160,192,160), win=9)
#define BB 2
#define DD 160
#define HH 192
#define WW 160
#define HW (HH * WW)
#define PAD 4
#define TH 16
#define TW 16
#define EXT 24              // TH+2*PAD == TW+2*PAD
#define XSTR 28             // plane row stride (words; rows 16B-aligned)
#define PLANE 768           // words per array plane (>= EXT*XSTR=672)
#define WCS 456             // wsum channel stride
#define WJS 28              // wsum j(col) stride (r contiguous, 16B-aligned)
#define HCS 272             // hsum channel stride
#define HHS 17              // hsum row stride (odd -> staggered)
#define CHUNK 19
#define NCH 9               // chunks: dc0 = 0,19,...,152 (last has 8 outputs)
#define NITER 27            // CHUNK + 2*PAD = 3*9 (static ring indexing)
#define WT (WW / TW)        // 10
#define HT (HH / TH)        // 12
#define NBLK (WT * HT * NCH * BB)  // 2160
#define NTASK 288           // staging float4 tasks per slice (2 arr x 24 r x 6 q)
#define EPS 1e-5f
#define INV_WS (1.0f / 729.0f)

// barrier that waits LDS only — never drains vmcnt (keeps prefetch in flight)
__device__ __forceinline__ void bar_lgkm() {
  asm volatile("s_waitcnt lgkmcnt(0)" ::: "memory");
  __builtin_amdgcn_s_barrier();
  asm volatile("" ::: "memory");
}

__global__ void __launch_bounds__(256, 6) k_lncc(
    const float* __restrict__ x, const float* __restrict__ y,
    float* __restrict__ partials)
{
  // Single-buffered planes: WAR between iter k+1's store (after bar C of k)
  // and iter k's P2 reads (before bar B of k) crosses a barrier -> safe.
  __shared__ __align__(16) float sbuf[2][PLANE];     // [arr] x,y  6144 B
  __shared__ __align__(16) float ones[32];
  __shared__ __align__(16) float wsum[5 * WCS];      // 9120 B  [c][j][r]
  __shared__ __align__(16) float hsum[5 * HCS];      // 5440 B  [c][h*HHS+w]
  __shared__ float red[4];

  const int t = threadIdx.x;
  const int w0 = blockIdx.x * TW;
  const int h0 = blockIdx.y * TH;
  const int bz = blockIdx.z;
  const int b = bz / NCH;
  const int chunk = bz - b * NCH;
  const int dc0 = chunk * CHUNK;
  const int g0 = dc0 - PAD;

  // ---- init: zero planes (OOB slots stay 0 forever); ones row ----
  for (int i = t; i < 2 * PLANE; i += 256) (&sbuf[0][0])[i] = 0.f;
  if (t < 32) ones[t] = 1.0f;
  __syncthreads();

  // ---- staging descriptors: NTASK float4 tasks; thread t gets t, 256+t ----
  int la0, la1; bool tk0, tk1;
  const float* gp0; const float* gp1;
  {
    const float* bx = x + (long)b * DD * HW;
    const float* by = y + (long)b * DD * HW;
#define MKTASK(TAU, LA, TK, GP)                                           \
    {                                                                     \
      int tau = (TAU);                                                    \
      int a = tau / 144;                                                  \
      int rem = tau - 144 * a;                                            \
      int r = rem / 6;                                                    \
      int q = rem - 6 * r;                                                \
      int aa = (a < 2) ? a : 0;                                           \
      int gh = h0 - PAD + r;                                              \
      int gw = w0 - PAD + 4 * q;                                          \
      bool ok = (tau < NTASK) && ((unsigned)gh < (unsigned)HH) &&         \
                ((unsigned)gw < (unsigned)WW);                            \
      LA = aa * PLANE + r * XSTR + 4 * q;                                 \
      TK = ok;                                                            \
      GP = (aa ? by : bx) + (ok ? (gh * WW + gw) : 0);                    \
    }
    MKTASK(t, la0, tk0, gp0)
    MKTASK(256 + t, la1, tk1, gp1)
#undef MKTASK
  }

  // ---- P2 constants (t<120): task = (channel c2, ext row r2) ----
  const int c2 = t / 24, r2 = t - c2 * 24;
  const int arrA = ((c2 == 1) || (c2 == 3)) ? 1 : 0;
  const int arrB = (c2 == 2) ? 0 : 1;
  const bool useOnes = (c2 < 2);
  const int paOff = arrA * PLANE + r2 * XSTR;
  const int pbOff = arrB * PLANE + r2 * XSTR;
  float* const wwr = &wsum[c2 * WCS + r2];      // + j*WJS

  // ---- P3 constants (t<80): task = (channel c3, out col w3) ----
  const int c3 = t / 16, w3 = t - c3 * 16;
  const float* const wrd = &wsum[c3 * WCS + w3 * WJS];  // + i contiguous
  float* const hwr = &hsum[c3 * HCS + w3];              // + h*HHS

  // ---- P4 constants: one output (h,w) per thread ----
  const int h4 = t >> 4, w4 = t & 15;
  const float* const hrd = &hsum[h4 * HHS + w4];        // + c*HCS

  // ---- D-window ring (static idx via jj), running sums ----
  float ring[9][5];
#pragma unroll
  for (int i = 0; i < 9; ++i)
#pragma unroll
    for (int c = 0; c < 5; ++c) ring[i][c] = 0.f;
  float run0 = 0.f, run1 = 0.f, run2 = 0.f, run3 = 0.f, run4 = 0.f, acc = 0.f;

  // ---- prologue: prefetch slice g0 into regs ----
  float4 st0 = make_float4(0, 0, 0, 0), st1 = st0;
  bool ps0 = false, ps1 = false;
  if (g0 >= 0) {
    const long so = (long)g0 * HW;
    ps0 = tk0; if (ps0) st0 = *(const float4*)(gp0 + so);
    ps1 = tk1; if (ps1) st1 = *(const float4*)(gp1 + so);
  }

  for (int ko = 0; ko < 3; ++ko) {
#pragma unroll
    for (int jj = 0; jj < 9; ++jj) {
      const int k = ko * 9 + jj;
      const int g = g0 + k;
      const bool gv = ((unsigned)g < (unsigned)DD);  // block-uniform
      float hv0 = 0.f, hv1 = 0.f, hv2 = 0.f, hv3 = 0.f, hv4 = 0.f;

      // store staged regs (slice k) -> planes; OOB lanes skip (pre-zeroed)
      if (gv) {
        float* lb = &sbuf[0][0];
        if (ps0) *(float4*)(lb + la0) = st0;
        if (ps1) *(float4*)(lb + la1) = st1;
      }
      // prefetch next slice (stays in flight across all barriers)
      {
        const int gn = g + 1;
        const bool nv = ((unsigned)gn < (unsigned)DD) && (k + 1 < NITER);
        const long so = (long)gn * HW;
        ps0 = tk0 && nv; if (ps0) st0 = *(const float4*)(gp0 + so);
        ps1 = tk1 && nv; if (ps1) st1 = *(const float4*)(gp1 + so);
      }

      if (gv) {
        bar_lgkm();  // A: planes visible
        // ---- P2: sliding W-filter (b128 row reads) ----
        if (t < 120) {
          const float* pa = &sbuf[0][0] + paOff;
          const float* pb = useOnes ? &ones[0] : (&sbuf[0][0] + pbOff);
          float4 A0 = *(const float4*)(pa);
          float4 A1 = *(const float4*)(pa + 4);
          float4 A2 = *(const float4*)(pa + 8);
          float4 A3 = *(const float4*)(pa + 12);
          float4 A4 = *(const float4*)(pa + 16);
          float4 A5 = *(const float4*)(pa + 20);
          float4 B0 = *(const float4*)(pb);
          float4 B1 = *(const float4*)(pb + (useOnes ? 0 : 4));
          float4 B2 = *(const float4*)(pb + (useOnes ? 0 : 8));
          float4 B3 = *(const float4*)(pb + (useOnes ? 0 : 12));
          float4 B4 = *(const float4*)(pb + (useOnes ? 0 : 16));
          float4 B5 = *(const float4*)(pb + (useOnes ? 0 : 20));
          float q[EXT];
          q[0]=A0.x*B0.x; q[1]=A0.y*B0.y; q[2]=A0.z*B0.z; q[3]=A0.w*B0.w;
          q[4]=A1.x*B1.x; q[5]=A1.y*B1.y; q[6]=A1.z*B1.z; q[7]=A1.w*B1.w;
          q[8]=A2.x*B2.x; q[9]=A2.y*B2.y; q[10]=A2.z*B2.z; q[11]=A2.w*B2.w;
          q[12]=A3.x*B3.x; q[13]=A3.y*B3.y; q[14]=A3.z*B3.z; q[15]=A3.w*B3.w;
          q[16]=A4.x*B4.x; q[17]=A4.y*B4.y; q[18]=A4.z*B4.z; q[19]=A4.w*B4.w;
          q[20]=A5.x*B5.x; q[21]=A5.y*B5.y; q[22]=A5.z*B5.z; q[23]=A5.w*B5.w;
          float s = ((q[0] + q[1]) + (q[2] + q[3])) +
                    ((q[4] + q[5]) + (q[6] + q[7])) + q[8];
          wwr[0] = s;
#pragma unroll
          for (int j = 1; j < TW; ++j) {
            s += q[j + 8] - q[j - 1];
            wwr[j * WJS] = s;
          }
        }
        bar_lgkm();  // B
        // ---- P3: sliding H-filter (b128 contiguous reads) ----
        if (t < 80) {
          float4 V0 = *(const float4*)(wrd);
          float4 V1 = *(const float4*)(wrd + 4);
          float4 V2 = *(const float4*)(wrd + 8);
          float4 V3 = *(const float4*)(wrd + 12);
          float4 V4 = *(const float4*)(wrd + 16);
          float4 V5 = *(const float4*)(wrd + 20);
          float v[EXT];
          v[0]=V0.x; v[1]=V0.y; v[2]=V0.z; v[3]=V0.w;
          v[4]=V1.x; v[5]=V1.y; v[6]=V1.z; v[7]=V1.w;
          v[8]=V2.x; v[9]=V2.y; v[10]=V2.z; v[11]=V2.w;
          v[12]=V3.x; v[13]=V3.y; v[14]=V3.z; v[15]=V3.w;
          v[16]=V4.x; v[17]=V4.y; v[18]=V4.z; v[19]=V4.w;
          v[20]=V5.x; v[21]=V5.y; v[22]=V5.z; v[23]=V5.w;
          float s = ((v[0] + v[1]) + (v[2] + v[3])) +
                    ((v[4] + v[5]) + (v[6] + v[7])) + v[8];
          hwr[0] = s;
#pragma unroll
          for (int h = 1; h < TH; ++h) {
            s += v[h + 8] - v[h - 1];
            hwr[h * HHS] = s;
          }
        }
        bar_lgkm();  // C
        hv0 = hrd[0];
        hv1 = hrd[HCS];
        hv2 = hrd[2 * HCS];
        hv3 = hrd[3 * HCS];
        hv4 = hrd[4 * HCS];
      }

      // ---- D running sums; ring[jj] static -> no register shifting ----
      run0 += hv0 - ring[jj][0]; ring[jj][0] = hv0;
      run1 += hv1 - ring[jj][1]; ring[jj][1] = hv1;
      run2 += hv2 - ring[jj][2]; ring[jj][2] = hv2;
      run3 += hv3 - ring[jj][3]; ring[jj][3] = hv3;
      run4 += hv4 - ring[jj][4]; ring[jj][4] = hv4;

      if (k >= 8) {
        const int d = dc0 + (k - 8);
        if (d < DD) {                   // block-uniform tail guard
          float cross = fmaf(-run0 * INV_WS, run1, run4);
          float xv = fmaxf(fmaf(-run0 * INV_WS, run0, run2), EPS);
          float yv = fmaxf(fmaf(-run1 * INV_WS, run1, run3), EPS);
          acc += (cross * cross) * __builtin_amdgcn_rcpf(xv * yv);
        }
      }
    }
  }

  // ---- block reduction ----
#pragma unroll
  for (int o = 32; o > 0; o >>= 1) acc += __shfl_down(acc, o);
  if ((t & 63) == 0) red[t >> 6] = acc;
  __syncthreads();
  if (t == 0) {
    int bid = (bz * HT + blockIdx.y) * WT + blockIdx.x;
    partials[bid] = (red[0] + red[1]) + (red[2] + red[3]);
  }
}

__global__ void __launch_bounds__(256) k_finalize(
    const float* __restrict__ partials, float* __restrict__ out)
{
  __shared__ double red[256];
  double s = 0.0;
  for (int i = threadIdx.x; i < NBLK; i += 256) s += (double)partials[i];
  red[threadIdx.x] = s;
  __syncthreads();
  for (int o = 128; o > 0; o >>= 1) {
    if (threadIdx.x < o) red[threadIdx.x] += red[threadIdx.x + o];
    __syncthreads();
  }
  if (threadIdx.x == 0) {
    const double Nvox = (double)BB * DD * HH * WW;
    out[0] = (float)(-red[0] / Nvox);
  }
}

extern "C" void kernel_launch(void* const* d_in, const int* in_sizes, int n_in,
                              void* d_out, int out_size, void* d_ws, size_t ws_size,
                              hipStream_t stream) {
  (void)in_sizes; (void)n_in; (void)out_size; (void)ws_size;
  const float* x = (const float*)d_in[0];
  const float* y = (const float*)d_in[1];
  float* out = (float*)d_out;
  float* partials = (float*)d_ws;

  dim3 grid(WT, HT, BB * NCH);
  k_lncc<<<grid, 256, 0, stream>>>(x, y, partials);
  k_finalize<<<1, 256, 0, stream>>>(partials, out);
}

// Round 12
// 77.793 us; speedup vs baseline: 4.5426x; 4.5426x over previous
//
#include <hip/hip_runtime.h>

// Problem constants (reference: shape (2,1,160,192,160), win=9)
#define BB 2
#define DD 160
#define HH 192
#define WW 160
#define HW (HH * WW)
#define PAD 4
#define TH 16
#define TW 16
#define EXT 24              // TH+2*PAD == TW+2*PAD
#define XSTR 28             // plane row stride (words; rows 16B-aligned)
#define PLANE 768           // words per array plane (>= EXT*XSTR=672)
#define WCS 456             // wsum channel stride
#define WJS 28              // wsum j(col) stride (r contiguous, 16B-aligned)
#define HCS 272             // hsum channel stride
#define HHS 17              // hsum row stride (odd -> staggered)
#define CHUNK 28
#define NCH 6               // ceil(DD/CHUNK)
#define NITER 36            // CHUNK + 2*PAD = 4*9 (static ring indexing)
#define WT (WW / TW)        // 10
#define HT (HH / TH)        // 12
#define NBLK (WT * HT * NCH * BB)  // 1440
#define NTASK 288           // staging float4 tasks per slice (2 arr x 24 r x 6 q)
#define EPS 1e-5f
#define INV_WS (1.0f / 729.0f)

// barrier that waits LDS only — never drains vmcnt (keeps prefetch in flight)
__device__ __forceinline__ void bar_lgkm() {
  asm volatile("s_waitcnt lgkmcnt(0)" ::: "memory");
  __builtin_amdgcn_s_barrier();
  asm volatile("" ::: "memory");
}

__global__ void __launch_bounds__(256) k_lncc(
    const float* __restrict__ x, const float* __restrict__ y,
    float* __restrict__ partials)
{
  // All LDS single-buffered; every RAW/WAR hazard crosses exactly one of the
  // two per-slice barriers (see schedule in the loop).
  __shared__ __align__(16) float sbuf[2][PLANE];     // [arr] x,y   6144 B
  __shared__ __align__(16) float ones[32];
  __shared__ __align__(16) float wsum[5 * WCS];      // 9120 B  [c][j][r]
  __shared__ __align__(16) float hsum[5 * HCS];      // 5440 B  [c][h*HHS+w]
  __shared__ float red[4];

  const int t = threadIdx.x;
  const int w0 = blockIdx.x * TW;
  const int h0 = blockIdx.y * TH;
  const int bz = blockIdx.z;
  const int b = bz / NCH;
  const int chunk = bz - b * NCH;
  const int dc0 = chunk * CHUNK;
  const int g0 = dc0 - PAD;

  // ---- init: zero planes (OOB slots stay 0 forever); ones row ----
  for (int i = t; i < 2 * PLANE; i += 256) (&sbuf[0][0])[i] = 0.f;
  if (t < 32) ones[t] = 1.0f;

  // ---- staging descriptors: NTASK float4 tasks; thread t gets t, 256+t ----
  int la0, la1; bool tk0, tk1;
  const float* gp0; const float* gp1;
  {
    const float* bx = x + (long)b * DD * HW;
    const float* by = y + (long)b * DD * HW;
#define MKTASK(TAU, LA, TK, GP)                                           \
    {                                                                     \
      int tau = (TAU);                                                    \
      int a = tau / 144;                                                  \
      int rem = tau - 144 * a;                                            \
      int r = rem / 6;                                                    \
      int q = rem - 6 * r;                                                \
      int aa = (a < 2) ? a : 0;                                           \
      int gh = h0 - PAD + r;                                              \
      int gw = w0 - PAD + 4 * q;                                          \
      bool ok = (tau < NTASK) && ((unsigned)gh < (unsigned)HH) &&         \
                ((unsigned)gw < (unsigned)WW);                            \
      LA = aa * PLANE + r * XSTR + 4 * q;                                 \
      TK = ok;                                                            \
      GP = (aa ? by : bx) + (ok ? (gh * WW + gw) : 0);                    \
    }
    MKTASK(t, la0, tk0, gp0)
    MKTASK(256 + t, la1, tk1, gp1)
#undef MKTASK
  }

  // ---- P2 constants (t<120): task = (channel c2, ext row r2) ----
  const int c2 = t / 24, r2 = t - c2 * 24;
  const int arrA = ((c2 == 1) || (c2 == 3)) ? 1 : 0;
  const int arrB = (c2 == 2) ? 0 : 1;
  const bool useOnes = (c2 < 2);
  const int paOff = arrA * PLANE + r2 * XSTR;
  const int pbOff = arrB * PLANE + r2 * XSTR;
  float* const wwr = &wsum[c2 * WCS + r2];      // + j*WJS

  // ---- P3 constants (t<80): task = (channel c3, out col w3) ----
  const int c3 = t / 16, w3 = t - c3 * 16;
  const float* const wrd = &wsum[c3 * WCS + w3 * WJS];  // + i contiguous
  float* const hwr = &hsum[c3 * HCS + w3];              // + h*HHS

  // ---- P4 constants: one output (h,w) per thread ----
  const int h4 = t >> 4, w4 = t & 15;
  const float* const hrd = &hsum[h4 * HHS + w4];        // + c*HCS

  // ---- D-window ring (static idx via jj), running sums ----
  float ring[9][5];
#pragma unroll
  for (int i = 0; i < 9; ++i)
#pragma unroll
    for (int c = 0; c < 5; ++c) ring[i][c] = 0.f;
  float run0 = 0.f, run1 = 0.f, run2 = 0.f, run3 = 0.f, run4 = 0.f, acc = 0.f;

  __syncthreads();   // zero-init visible before any staging store

  // ---- prologue: store slice 0 directly; prefetch slice 1 into regs ----
  float4 st0 = make_float4(0, 0, 0, 0), st1 = st0;
  bool ps0 = false, ps1 = false;
  {
    if ((unsigned)g0 < (unsigned)DD) {
      const long so = (long)g0 * HW;
      if (tk0) *(float4*)&sbuf[0][la0] = *(const float4*)(gp0 + so);
      if (tk1) *(float4*)&sbuf[0][la1] = *(const float4*)(gp1 + so);
    }
    const int g1i = g0 + 1;
    const bool v1 = ((unsigned)g1i < (unsigned)DD);
    const long so1 = (long)g1i * HW;
    ps0 = tk0 && v1; if (ps0) st0 = *(const float4*)(gp0 + so1);
    ps1 = tk1 && v1; if (ps1) st1 = *(const float4*)(gp1 + so1);
  }
  __syncthreads();   // slice-0 stores visible

  // ---- main loop: iter k = { P2(k) | barB | store(k+1) + prefetch(k+2) +
  //                            P3(k) | barC | P4(k) }  — 2 barriers/slice
  for (int ko = 0; ko < 4; ++ko) {
#pragma unroll
    for (int jj = 0; jj < 9; ++jj) {
      const int k = ko * 9 + jj;
      const int g = g0 + k;
      const bool gv = ((unsigned)g < (unsigned)DD);  // block-uniform

      // ---- P2(k): sliding W-filter (b128 row reads of sbuf) ----
      if (gv && t < 120) {
        const float* pa = &sbuf[0][0] + paOff;
        const float* pb = useOnes ? &ones[0] : (&sbuf[0][0] + pbOff);
        float4 A0 = *(const float4*)(pa);
        float4 A1 = *(const float4*)(pa + 4);
        float4 A2 = *(const float4*)(pa + 8);
        float4 A3 = *(const float4*)(pa + 12);
        float4 A4 = *(const float4*)(pa + 16);
        float4 A5 = *(const float4*)(pa + 20);
        float4 B0 = *(const float4*)(pb);
        float4 B1 = *(const float4*)(pb + (useOnes ? 0 : 4));
        float4 B2 = *(const float4*)(pb + (useOnes ? 0 : 8));
        float4 B3 = *(const float4*)(pb + (useOnes ? 0 : 12));
        float4 B4 = *(const float4*)(pb + (useOnes ? 0 : 16));
        float4 B5 = *(const float4*)(pb + (useOnes ? 0 : 20));
        float q[EXT];
        q[0]=A0.x*B0.x; q[1]=A0.y*B0.y; q[2]=A0.z*B0.z; q[3]=A0.w*B0.w;
        q[4]=A1.x*B1.x; q[5]=A1.y*B1.y; q[6]=A1.z*B1.z; q[7]=A1.w*B1.w;
        q[8]=A2.x*B2.x; q[9]=A2.y*B2.y; q[10]=A2.z*B2.z; q[11]=A2.w*B2.w;
        q[12]=A3.x*B3.x; q[13]=A3.y*B3.y; q[14]=A3.z*B3.z; q[15]=A3.w*B3.w;
        q[16]=A4.x*B4.x; q[17]=A4.y*B4.y; q[18]=A4.z*B4.z; q[19]=A4.w*B4.w;
        q[20]=A5.x*B5.x; q[21]=A5.y*B5.y; q[22]=A5.z*B5.z; q[23]=A5.w*B5.w;
        float s = ((q[0] + q[1]) + (q[2] + q[3])) +
                  ((q[4] + q[5]) + (q[6] + q[7])) + q[8];
        wwr[0] = s;
#pragma unroll
        for (int j = 1; j < TW; ++j) {
          s += q[j + 8] - q[j - 1];
          wwr[j * WJS] = s;
        }
      }

      bar_lgkm();  // B: P2 reads of sbuf done -> store(k+1) is WAR-safe;
                   //    wsum writes visible for P3

      // ---- store slice k+1 -> sbuf (predicated; overlaps P3) ----
      if (ps0) *(float4*)&sbuf[0][la0] = st0;
      if (ps1) *(float4*)&sbuf[0][la1] = st1;

      // ---- prefetch slice k+2 into regs (in flight across barriers) ----
      {
        const int gn = g + 2;
        const bool nv = (k + 2 < NITER) && ((unsigned)gn < (unsigned)DD);
        const long so = (long)gn * HW;
        ps0 = tk0 && nv; if (ps0) st0 = *(const float4*)(gp0 + so);
        ps1 = tk1 && nv; if (ps1) st1 = *(const float4*)(gp1 + so);
      }

      // ---- P3(k): sliding H-filter (b128 contiguous reads of wsum) ----
      if (gv && t < 80) {
        float4 V0 = *(const float4*)(wrd);
        float4 V1 = *(const float4*)(wrd + 4);
        float4 V2 = *(const float4*)(wrd + 8);
        float4 V3 = *(const float4*)(wrd + 12);
        float4 V4 = *(const float4*)(wrd + 16);
        float4 V5 = *(const float4*)(wrd + 20);
        float v[EXT];
        v[0]=V0.x; v[1]=V0.y; v[2]=V0.z; v[3]=V0.w;
        v[4]=V1.x; v[5]=V1.y; v[6]=V1.z; v[7]=V1.w;
        v[8]=V2.x; v[9]=V2.y; v[10]=V2.z; v[11]=V2.w;
        v[12]=V3.x; v[13]=V3.y; v[14]=V3.z; v[15]=V3.w;
        v[16]=V4.x; v[17]=V4.y; v[18]=V4.z; v[19]=V4.w;
        v[20]=V5.x; v[21]=V5.y; v[22]=V5.z; v[23]=V5.w;
        float s = ((v[0] + v[1]) + (v[2] + v[3])) +
                  ((v[4] + v[5]) + (v[6] + v[7])) + v[8];
        hwr[0] = s;
#pragma unroll
        for (int h = 1; h < TH; ++h) {
          s += v[h + 8] - v[h - 1];
          hwr[h * HHS] = s;
        }
      }

      bar_lgkm();  // C: hsum visible for P4; sbuf store visible for next P2;
                   //    P3's wsum reads done -> next P2 wsum writes WAR-safe

      // ---- P4(k): per-output channel reads + ring + cc ----
      float hv0 = 0.f, hv1 = 0.f, hv2 = 0.f, hv3 = 0.f, hv4 = 0.f;
      if (gv) {
        hv0 = hrd[0];
        hv1 = hrd[HCS];
        hv2 = hrd[2 * HCS];
        hv3 = hrd[3 * HCS];
        hv4 = hrd[4 * HCS];
        // P4 reads complete before barB(k+1) -> P3(k+1) hsum writes WAR-safe
      }

      run0 += hv0 - ring[jj][0]; ring[jj][0] = hv0;
      run1 += hv1 - ring[jj][1]; ring[jj][1] = hv1;
      run2 += hv2 - ring[jj][2]; ring[jj][2] = hv2;
      run3 += hv3 - ring[jj][3]; ring[jj][3] = hv3;
      run4 += hv4 - ring[jj][4]; ring[jj][4] = hv4;

      if (k >= 8) {
        const int d = dc0 + (k - 8);
        if (d < DD) {                   // block-uniform tail guard
          float cross = fmaf(-run0 * INV_WS, run1, run4);
          float xv = fmaxf(fmaf(-run0 * INV_WS, run0, run2), EPS);
          float yv = fmaxf(fmaf(-run1 * INV_WS, run1, run3), EPS);
          acc += (cross * cross) * __builtin_amdgcn_rcpf(xv * yv);
        }
      }
    }
  }

  // ---- block reduction ----
#pragma unroll
  for (int o = 32; o > 0; o >>= 1) acc += __shfl_down(acc, o);
  if ((t & 63) == 0) red[t >> 6] = acc;
  __syncthreads();
  if (t == 0) {
    int bid = (bz * HT + blockIdx.y) * WT + blockIdx.x;
    partials[bid] = (red[0] + red[1]) + (red[2] + red[3]);
  }
}

__global__ void __launch_bounds__(256) k_finalize(
    const float* __restrict__ partials, float* __restrict__ out)
{
  __shared__ double red[256];
  double s = 0.0;
  for (int i = threadIdx.x; i < NBLK; i += 256) s += (double)partials[i];
  red[threadIdx.x] = s;
  __syncthreads();
  for (int o = 128; o > 0; o >>= 1) {
    if (threadIdx.x < o) red[threadIdx.x] += red[threadIdx.x + o];
    __syncthreads();
  }
  if (threadIdx.x == 0) {
    const double Nvox = (double)BB * DD * HH * WW;
    out[0] = (float)(-red[0] / Nvox);
  }
}

extern "C" void kernel_launch(void* const* d_in, const int* in_sizes, int n_in,
                              void* d_out, int out_size, void* d_ws, size_t ws_size,
                              hipStream_t stream) {
  (void)in_sizes; (void)n_in; (void)out_size; (void)ws_size;
  const float* x = (const float*)d_in[0];
  const float* y = (const float*)d_in[1];
  float* out = (float*)d_out;
  float* partials = (float*)d_ws;

  dim3 grid(WT, HT, BB * NCH);
  k_lncc<<<grid, 256, 0, stream>>>(x, y, partials);
  k_finalize<<<1, 256, 0, stream>>>(partials, out);
}